// Round 1
// baseline (23778.668 us; speedup 1.0000x reference)
//
#include <hip/hip_runtime.h>

// ---------------- problem constants ----------------
#define T_SEQ 8192
#define HDIM  256
#define VOC   28
#define LAT   32
#define CDIM  8

// ---------------- decomposition ----------------
#define NWG   16      // persistent workgroups (must all be co-resident; 16 << 256 CUs)
#define NTHR  512     // threads per WG (8 waves)
#define NROW  64      // gate rows per WG (1024 / NWG)
#define NCH   8       // chunks per row == waves
#define WCH   32      // weights per thread per matrix (256 / NCH)

#define OUT_PRED (T_SEQ)
#define OUT_MEAN (T_SEQ + T_SEQ*VOC)
#define OUT_LV   (OUT_MEAN + LAT)

__device__ __forceinline__ float sigm(float x){
  x = fminf(fmaxf(x, -30.f), 30.f);
  return 1.f/(1.f + __expf(-x));
}
__device__ __forceinline__ float tanhfast(float x){
  x = fminf(fmaxf(x, -15.f), 15.f);
  float e = __expf(2.f*x);
  return (e-1.f)/(e+1.f);
}

// Persistent kernel: 16 WGs run both LSTM scans, exchanging h each step via
// packed (tag,h) 8B device-scope atomics in d_ws. Whh slices live in VGPRs.
__global__ __launch_bounds__(NTHR, 1)
void cvae_persist(
    const int* __restrict__ input, const int* __restrict__ tense_p, const float* __restrict__ eps,
    const float* __restrict__ enc_embed, const float* __restrict__ enc_wih, const float* __restrict__ enc_whh,
    const float* __restrict__ enc_bih, const float* __restrict__ enc_bhh,
    const float* __restrict__ dec_embed, const float* __restrict__ dec_wih, const float* __restrict__ dec_whh,
    const float* __restrict__ dec_bih, const float* __restrict__ dec_bhh,
    const float* __restrict__ h2m_w, const float* __restrict__ h2m_b,
    const float* __restrict__ h2v_w, const float* __restrict__ h2v_b,
    const float* __restrict__ cond_embed, const float* __restrict__ lat2emb_w, const float* __restrict__ lat2emb_b,
    float* __restrict__ d_out, unsigned long long* __restrict__ hb, float* __restrict__ hs)
{
  __shared__ float hlds[HDIM];          // current h (staged each step)
  __shared__ float pbuf[NROW*9];        // partial sums, stride 9 to dodge bank conflicts
  __shared__ float tbl[2][VOC*NROW];    // per-vocab input-gate tables (enc,dec)
  __shared__ unsigned char toks[T_SEQ];
  __shared__ float lat[LAT+CDIM];

  const int w   = blockIdx.x;
  const int tid = threadIdx.x;
  const int c   = tid >> 6;             // chunk == wave id
  const int r   = tid & 63;             // row within WG (lane)
  // global gate-row: gate g=r>>4, h-index k = w*16 + (r&15)
  const int R   = ((r>>4)<<8) + (w<<4) + (r&15);

  // ---- token list into LDS (as bytes) ----
  for (int i = tid; i < T_SEQ; i += NTHR) toks[i] = (unsigned char)input[i];

  // ---- per-vocab input tables: tbl[ph][v*64+r] = Wih[R,:]@x_v + bih[R]+bhh[R] ----
  {
    float wtmp[WCH];
    for (int ph = 0; ph < 2; ++ph){
      const float* wih = ph ? dec_wih   : enc_wih;
      const float* emb = ph ? dec_embed : enc_embed;
      const float* bih = ph ? dec_bih   : enc_bih;
      const float* bhh = ph ? dec_bhh   : enc_bhh;
      #pragma unroll
      for (int j = 0; j < WCH; ++j) wtmp[j] = wih[(size_t)R*HDIM + c*WCH + j];
      #pragma unroll 1
      for (int v = 0; v < VOC; ++v){
        float p = 0.f;
        const float* xr = emb + v*HDIM + c*WCH;
        #pragma unroll
        for (int j = 0; j < WCH; ++j){
          float x = xr[j];
          if (ph) x = fmaxf(x, 0.f);          // decoder: relu(embed)
          p += wtmp[j]*x;
        }
        pbuf[r*9 + c] = p;
        __syncthreads();
        if (tid < NROW){
          float s = 0.f;
          #pragma unroll
          for (int q = 0; q < NCH; ++q) s += pbuf[tid*9 + q];
          tbl[ph][v*NROW + tid] = s + bih[R] + bhh[R];
        }
        __syncthreads();
      }
    }
  }

  // ---- recurrent weight slices -> VGPRs ----
  float wenc[WCH], wdec[WCH];
  #pragma unroll
  for (int j = 0; j < WCH; ++j){
    wenc[j] = enc_whh[(size_t)R*HDIM + c*WCH + j];
    wdec[j] = dec_whh[(size_t)R*HDIM + c*WCH + j];
  }

  // ---- encoder init: h0 = [0...; cond], c0 = 0 ----
  const int tense = tense_p[0];
  if (tid < HDIM)
    hlds[tid] = (tid >= HDIM-CDIM) ? cond_embed[tense*CDIM + (tid-(HDIM-CDIM))] : 0.f;
  float cst = 0.f;                       // cell state, valid in wave0 lanes<16
  __syncthreads();

  // ---- one LSTM step ----
  auto step = [&](int t, const float (&wv)[WCH], int tok, int isdec, int srow){
    // all waves: partial dot of own rows vs h chunk (LDS broadcast reads)
    float p = 0.f;
    #pragma unroll
    for (int j = 0; j < WCH; ++j) p += wv[j]*hlds[c*WCH + j];
    pbuf[r*9 + c] = p;
    __syncthreads();

    if (c == 0){
      // wave0: reduce chunks, add input-table term, gate math, publish own slice
      float s = 0.f;
      #pragma unroll
      for (int q = 0; q < NCH; ++q) s += pbuf[r*9 + q];
      s += tbl[isdec][tok*NROW + r];
      const int kk = r & 15;
      float gi = __shfl(s, kk);
      float gf = __shfl(s, kk+16);
      float gg = __shfl(s, kk+32);
      float go = __shfl(s, kk+48);
      float c2 = sigm(gf)*cst + sigm(gi)*tanhfast(gg);
      float h2 = sigm(go)*tanhfast(c2);
      if (r < 16){
        cst = c2;
        hlds[(w<<4) + r] = h2;           // own slice staged locally (off critical path)
        unsigned long long pr =
            (((unsigned long long)(unsigned int)t) << 32) |
             (unsigned long long)__float_as_uint(h2);
        __hip_atomic_store(&hb[((t&1)<<8) + (w<<4) + r], pr,
                           __ATOMIC_RELAXED, __HIP_MEMORY_SCOPE_AGENT);
        if (isdec) hs[(size_t)srow*HDIM + (w<<4) + r] = h2;
      }
    } else if (c == 1){
      // wave1 (concurrent with wave0's serial part): poll remote slices
      unsigned long long vals[4];
      const int base = (t&1) << 8;
      for (;;){
        int ok = 1;
        #pragma unroll
        for (int q = 0; q < 4; ++q){
          const int slot = (r<<2) + q;
          vals[q] = __hip_atomic_load(&hb[base + slot],
                                      __ATOMIC_RELAXED, __HIP_MEMORY_SCOPE_AGENT);
          if (((slot>>4) != w) && ((int)(vals[q] >> 32) < t)) ok = 0;
        }
        if (__all(ok)) break;
      }
      #pragma unroll
      for (int q = 0; q < 4; ++q){
        const int slot = (r<<2) + q;
        if ((slot>>4) != w) hlds[slot] = __uint_as_float((unsigned int)vals[q]);
      }
    }
    __syncthreads();
  };

  // ---- encoder scan: tags 1..T ----
  #pragma unroll 1
  for (int s = 0; s < T_SEQ; ++s)
    step(s+1, wenc, (int)toks[s], 0, 0);

  // ---- middle phase (computed redundantly by every WG; no exchange needed) ----
  {
    const float* wm = (r < 32) ? (h2m_w + (size_t)r*HDIM) : (h2v_w + (size_t)(r-32)*HDIM);
    float p = 0.f;
    #pragma unroll
    for (int j = 0; j < WCH; ++j) p += wm[c*WCH + j]*hlds[c*WCH + j];
    pbuf[r*9 + c] = p;
    __syncthreads();
    if (c == 0){
      float s = 0.f;
      #pragma unroll
      for (int q = 0; q < NCH; ++q) s += pbuf[r*9 + q];
      s += (r < 32) ? h2m_b[r] : h2v_b[r-32];
      float other = __shfl(s, (r&31) + 32);   // lanes<32 fetch log_var
      if (r < 32){
        float mean = s, lv = other;
        lat[r] = eps[r]*__expf(0.5f*lv) + mean;     // reparameterize
        if (w == 0){
          d_out[OUT_MEAN + r] = mean;
          d_out[OUT_LV   + r] = lv;
        }
      }
      if (r < CDIM) lat[LAT + r] = cond_embed[tense*CDIM + r];
      if (r < 16)   cst = 0.f;                       // decoder c0 = 0
    }
    __syncthreads();
    float dh = 0.f;
    if (tid < HDIM){
      dh = lat2emb_b[tid];
      #pragma unroll
      for (int j = 0; j < LAT+CDIM; ++j) dh += lat2emb_w[tid*(LAT+CDIM) + j]*lat[j];
    }
    __syncthreads();
    if (tid < HDIM) hlds[tid] = dh;                 // decoder h0
    __syncthreads();
  }

  // ---- decoder scan: tags T+1..2T; teacher forcing: tok = [SOS, input[0..T-2]] ----
  #pragma unroll 1
  for (int s = 0; s < T_SEQ; ++s){
    const int tok = s ? (int)toks[s-1] : 0;         // SOS = 0
    step(T_SEQ + 1 + s, wdec, tok, 1, s);
  }
}

// Output projection + argmax over the stored decoder states (fully parallel).
__global__ __launch_bounds__(256, 1)
void cvae_proj(const float* __restrict__ hs, const float* __restrict__ out_w,
               const float* __restrict__ out_b, float* __restrict__ d_out)
{
  __shared__ float ow[VOC*HDIM];   // 28 KB
  __shared__ float ob[VOC];
  const int tid = threadIdx.x;
  for (int i = tid; i < VOC*HDIM; i += 256) ow[i] = out_w[i];
  if (tid < VOC) ob[tid] = out_b[tid];
  __syncthreads();

  const int t = blockIdx.x*256 + tid;
  const float* hr = hs + (size_t)t*HDIM;
  float acc[VOC];
  #pragma unroll
  for (int v = 0; v < VOC; ++v) acc[v] = ob[v];
  #pragma unroll 4
  for (int j = 0; j < HDIM; j += 4){
    float4 h4 = *(const float4*)(hr + j);
    #pragma unroll
    for (int v = 0; v < VOC; ++v){
      acc[v] += h4.x*ow[v*HDIM + j]     + h4.y*ow[v*HDIM + j + 1]
              + h4.z*ow[v*HDIM + j + 2] + h4.w*ow[v*HDIM + j + 3];
    }
  }
  float best = acc[0]; int bi = 0;
  #pragma unroll
  for (int v = 1; v < VOC; ++v){ if (acc[v] > best){ best = acc[v]; bi = v; } }
  float* pd = d_out + OUT_PRED + (size_t)t*VOC;
  #pragma unroll
  for (int v = 0; v < VOC; ++v) pd[v] = acc[v];
  d_out[t] = (float)bi;                    // first-occurrence argmax, as float
}

extern "C" void kernel_launch(void* const* d_in, const int* in_sizes, int n_in,
                              void* d_out, int out_size, void* d_ws, size_t ws_size,
                              hipStream_t stream)
{
  const int*   input     = (const int*)  d_in[0];
  const int*   tense     = (const int*)  d_in[1];
  const float* eps       = (const float*)d_in[2];
  const float* enc_embed = (const float*)d_in[3];
  const float* enc_wih   = (const float*)d_in[4];
  const float* enc_whh   = (const float*)d_in[5];
  const float* enc_bih   = (const float*)d_in[6];
  const float* enc_bhh   = (const float*)d_in[7];
  const float* dec_embed = (const float*)d_in[8];
  const float* dec_wih   = (const float*)d_in[9];
  const float* dec_whh   = (const float*)d_in[10];
  const float* dec_bih   = (const float*)d_in[11];
  const float* dec_bhh   = (const float*)d_in[12];
  const float* out_w     = (const float*)d_in[13];
  const float* out_b     = (const float*)d_in[14];
  const float* h2m_w     = (const float*)d_in[15];
  const float* h2m_b     = (const float*)d_in[16];
  const float* h2v_w     = (const float*)d_in[17];
  const float* h2v_b     = (const float*)d_in[18];
  const float* cond_embed= (const float*)d_in[19];
  const float* lat2emb_w = (const float*)d_in[20];
  const float* lat2emb_b = (const float*)d_in[21];

  // ws layout: [0,4096) (tag,h) exchange buffer (2 parities x 256 slots x 8B)
  //            [4096, 4096 + 8 MB) decoder hidden-state history
  unsigned long long* hb = (unsigned long long*)d_ws;
  float* hs = (float*)((char*)d_ws + 4096);

  // Zero the exchange tags so stale/poisoned tags can never satisfy a poll.
  hipMemsetAsync(d_ws, 0, 4096, stream);

  hipLaunchKernelGGL(cvae_persist, dim3(NWG), dim3(NTHR), 0, stream,
      input, tense, eps, enc_embed, enc_wih, enc_whh, enc_bih, enc_bhh,
      dec_embed, dec_wih, dec_whh, dec_bih, dec_bhh,
      h2m_w, h2m_b, h2v_w, h2v_b, cond_embed, lat2emb_w, lat2emb_b,
      (float*)d_out, hb, hs);

  hipLaunchKernelGGL(cvae_proj, dim3(T_SEQ/256), dim3(256), 0, stream,
      hs, out_w, out_b, (float*)d_out);
}